// Round 1
// baseline (25397.694 us; speedup 1.0000x reference)
//
#include <hip/hip_runtime.h>
#include <hip/hip_bf16.h>

#define TS 256
#define BB 128
#define II 1024
#define HH 1024
#define PP 512
#define GG 4096  // 4*H

__device__ __forceinline__ float cvt(const float* p, long i) { return p[i]; }
__device__ __forceinline__ float cvt(const __hip_bfloat16* p, long i) { return __bfloat162float(p[i]); }
__device__ __forceinline__ void stv(float* p, long i, float v) { p[i] = v; }
__device__ __forceinline__ void stv(__hip_bfloat16* p, long i, float v) { p[i] = __float2bfloat16(v); }

// C[M,N] = A[M,K] @ B[N,K]^T  (B row-major [N,K])
// 64x64 tile, BK=16, 256 threads, 4x4 per thread. Requires M%64==0, N%64==0, K%16==0.
template <typename ATy, typename BTy, typename CTy>
__global__ __launch_bounds__(256) void gemm_bt_k(const ATy* __restrict__ A,
                                                 const BTy* __restrict__ B,
                                                 CTy* __restrict__ C,
                                                 int M, int N, int K) {
    __shared__ float As[16][65];
    __shared__ float Bs[16][65];
    const int tid = threadIdx.x;
    const int bm = blockIdx.y * 64;
    const int bn = blockIdx.x * 64;
    const int r  = tid >> 2;        // 0..63
    const int kq = (tid & 3) * 4;   // 0,4,8,12
    const int ty = tid >> 4;        // 0..15
    const int tx = tid & 15;        // 0..15
    float acc[4][4] = {};
    for (int k0 = 0; k0 < K; k0 += 16) {
        long abase = (long)(bm + r) * K + k0 + kq;
        long bbase = (long)(bn + r) * K + k0 + kq;
        float a0 = cvt(A, abase+0), a1 = cvt(A, abase+1), a2 = cvt(A, abase+2), a3 = cvt(A, abase+3);
        float b0 = cvt(B, bbase+0), b1 = cvt(B, bbase+1), b2 = cvt(B, bbase+2), b3 = cvt(B, bbase+3);
        As[kq+0][r] = a0; As[kq+1][r] = a1; As[kq+2][r] = a2; As[kq+3][r] = a3;
        Bs[kq+0][r] = b0; Bs[kq+1][r] = b1; Bs[kq+2][r] = b2; Bs[kq+3][r] = b3;
        __syncthreads();
        #pragma unroll
        for (int kk = 0; kk < 16; ++kk) {
            float av[4], bv[4];
            #pragma unroll
            for (int i2 = 0; i2 < 4; ++i2) av[i2] = As[kk][ty*4+i2];
            #pragma unroll
            for (int j = 0; j < 4; ++j) bv[j] = Bs[kk][tx*4+j];
            #pragma unroll
            for (int i2 = 0; i2 < 4; ++i2)
                #pragma unroll
                for (int j = 0; j < 4; ++j)
                    acc[i2][j] += av[i2]*bv[j];
        }
        __syncthreads();
    }
    #pragma unroll
    for (int i2 = 0; i2 < 4; ++i2) {
        long row = (long)(bm + ty*4 + i2) * N + bn;
        #pragma unroll
        for (int j = 0; j < 4; ++j) stv(C, row + tx*4 + j, acc[i2][j]);
    }
}

// C[M,N] = A[M,K] @ B[K,N]  (both row-major)
template <typename ATy, typename BTy, typename CTy>
__global__ __launch_bounds__(256) void gemm_nn_k(const ATy* __restrict__ A,
                                                 const BTy* __restrict__ B,
                                                 CTy* __restrict__ C,
                                                 int M, int N, int K) {
    __shared__ float As[16][65];
    __shared__ float Bs[16][65];
    const int tid = threadIdx.x;
    const int bm = blockIdx.y * 64;
    const int bn = blockIdx.x * 64;
    const int r  = tid >> 2;
    const int kq = (tid & 3) * 4;
    const int ty = tid >> 4;
    const int tx = tid & 15;
    float acc[4][4] = {};
    for (int k0 = 0; k0 < K; k0 += 16) {
        long abase = (long)(bm + r) * K + k0 + kq;
        float a0 = cvt(A, abase+0), a1 = cvt(A, abase+1), a2 = cvt(A, abase+2), a3 = cvt(A, abase+3);
        As[kq+0][r] = a0; As[kq+1][r] = a1; As[kq+2][r] = a2; As[kq+3][r] = a3;
        // B loader: kk = tid>>4 (0..15), c = (tid&15)*4
        {
            int kk = tid >> 4;
            int c  = (tid & 15) * 4;
            long bbase = (long)(k0 + kk) * N + bn + c;
            float b0 = cvt(B, bbase+0), b1 = cvt(B, bbase+1), b2 = cvt(B, bbase+2), b3 = cvt(B, bbase+3);
            Bs[kk][c+0] = b0; Bs[kk][c+1] = b1; Bs[kk][c+2] = b2; Bs[kk][c+3] = b3;
        }
        __syncthreads();
        #pragma unroll
        for (int kk = 0; kk < 16; ++kk) {
            float av[4], bv[4];
            #pragma unroll
            for (int i2 = 0; i2 < 4; ++i2) av[i2] = As[kk][ty*4+i2];
            #pragma unroll
            for (int j = 0; j < 4; ++j) bv[j] = Bs[kk][tx*4+j];
            #pragma unroll
            for (int i2 = 0; i2 < 4; ++i2)
                #pragma unroll
                for (int j = 0; j < 4; ++j)
                    acc[i2][j] += av[i2]*bv[j];
        }
        __syncthreads();
    }
    #pragma unroll
    for (int i2 = 0; i2 < 4; ++i2) {
        long row = (long)(bm + ty*4 + i2) * N + bn;
        #pragma unroll
        for (int j = 0; j < 4; ++j) stv(C, row + tx*4 + j, acc[i2][j]);
    }
}

// Elementwise LSTM cell: gates(gemm result, fp32) + xg_t(bf16) -> activations,
// c update, h_full out (bf16). Gate order i,f,g,o along 4H.
__global__ __launch_bounds__(256) void lstm_cell_k(const float* __restrict__ gates,
                                                   const __hip_bfloat16* __restrict__ xg_t,
                                                   const float* __restrict__ c_in,
                                                   float* __restrict__ c_out,
                                                   __hip_bfloat16* __restrict__ h_out) {
    int idx = blockIdx.x * 256 + threadIdx.x;   // [0, B*H)
    int b = idx >> 10;
    int h = idx & 1023;
    long gb = (long)b * GG;
    float gi = gates[gb + h]        + cvt(xg_t, gb + h);
    float gf = gates[gb + 1024 + h] + cvt(xg_t, gb + 1024 + h);
    float gg = gates[gb + 2048 + h] + cvt(xg_t, gb + 2048 + h);
    float go = gates[gb + 3072 + h] + cvt(xg_t, gb + 3072 + h);
    float i_ = 1.0f / (1.0f + expf(-gi));
    float f_ = 1.0f / (1.0f + expf(-gf));
    float g_ = tanhf(gg);
    float o_ = 1.0f / (1.0f + expf(-go));
    float c  = f_ * c_in[idx] + i_ * g_;
    c_out[idx] = c;
    h_out[idx] = __float2bfloat16(o_ * tanhf(c));
}

__global__ __launch_bounds__(256) void tail_k(const float* __restrict__ ys_last,
                                              const float* __restrict__ cstate,
                                              float* __restrict__ hT,
                                              float* __restrict__ cT) {
    int i = blockIdx.x * 256 + threadIdx.x;  // grid covers B*H
    if (i < BB * PP) hT[i] = ys_last[i];
    cT[i] = cstate[i];
}

extern "C" void kernel_launch(void* const* d_in, const int* in_sizes, int n_in,
                              void* d_out, int out_size, void* d_ws, size_t ws_size,
                              hipStream_t stream) {
    const float* x   = (const float*)d_in[0];  // [T,B,I]
    const float* h0  = (const float*)d_in[1];  // [1,B,P]
    const float* c0  = (const float*)d_in[2];  // [1,B,H]
    const float* Wih = (const float*)d_in[3];  // [4H,I]
    const float* Whh = (const float*)d_in[4];  // [4H,P]
    const float* Whr = (const float*)d_in[5];  // [P,H]

    float* out = (float*)d_out;
    float* ys = out;                                  // [T,B,P]
    float* hT = out + (long)TS * BB * PP;             // [B,P]
    float* cT = hT + (long)BB * PP;                   // [B,H]

    char* ws = (char*)d_ws;
    size_t off = 0;
    __hip_bfloat16* xg = (__hip_bfloat16*)(ws + off);           off += (size_t)TS * BB * GG * 2;  // 256 MB
    __hip_bfloat16* hfull = (__hip_bfloat16*)(ws + off);        off += (size_t)TS * BB * HH * 2;  // 64 MB
    __hip_bfloat16* Wcomb = (__hip_bfloat16*)(ws + off);        off += (size_t)GG * HH * 2;       // 8 MB
    float* gates = (float*)(ws + off);                          off += (size_t)BB * GG * 4;       // 2 MB
    float* cst = (float*)(ws + off);                            off += (size_t)BB * HH * 4;       // 0.5 MB

    dim3 blk(256);

    // 1) xg[T*B, 4H] = x @ W_ih^T  (parallel, bf16 out)
    gemm_bt_k<float, float, __hip_bfloat16>
        <<<dim3(GG / 64, (TS * BB) / 64), blk, 0, stream>>>(x, Wih, xg, TS * BB, GG, II);

    // 2) W_comb[4H, H] = W_hh @ W_hr  (exact refactor: folds projection into recurrence)
    gemm_nn_k<float, float, __hip_bfloat16>
        <<<dim3(HH / 64, GG / 64), blk, 0, stream>>>(Whh, Whr, Wcomb, GG, HH, PP);

    // 3) t = 0: gates = h0 @ W_hh^T (h0 is already the projected state)
    gemm_bt_k<float, float, float>
        <<<dim3(GG / 64, BB / 64), blk, 0, stream>>>(h0, Whh, gates, BB, GG, PP);
    lstm_cell_k<<<dim3((BB * HH) / 256), blk, 0, stream>>>(gates, xg, c0, cst, hfull);

    // 4) t = 1..T-1: gates = h_full[t-1] @ W_comb^T
    for (int t = 1; t < TS; ++t) {
        gemm_bt_k<__hip_bfloat16, __hip_bfloat16, float>
            <<<dim3(GG / 64, BB / 64), blk, 0, stream>>>(
                hfull + (long)(t - 1) * BB * HH, Wcomb, gates, BB, GG, HH);
        lstm_cell_k<<<dim3((BB * HH) / 256), blk, 0, stream>>>(
            gates, xg + (long)t * BB * GG, cst, cst, hfull + (long)t * BB * HH);
    }

    // 5) ys[T*B, P] = h_full_hist @ W_hr^T  (parallel, fp32 out to d_out)
    gemm_bt_k<__hip_bfloat16, float, float>
        <<<dim3(PP / 64, (TS * BB) / 64), blk, 0, stream>>>(hfull, Whr, ys, TS * BB, PP, HH);

    // 6) hT = ys[T-1], cT = c state
    tail_k<<<dim3((BB * HH) / 256), blk, 0, stream>>>(
        ys + (long)(TS - 1) * BB * PP, cst, hT, cT);
}

// Round 2
// 18221.535 us; speedup vs baseline: 1.3938x; 1.3938x over previous
//
#include <hip/hip_runtime.h>
#include <hip/hip_bf16.h>
#include <hip/hip_cooperative_groups.h>

#define TS 256
#define BB 128
#define II 1024
#define HH 1024
#define PP 512
#define GG 4096  // 4*H

typedef __attribute__((ext_vector_type(8))) short bf16x8;
typedef __attribute__((ext_vector_type(4))) float f32x4;

__device__ __forceinline__ short f2bs(float f) {
    __hip_bfloat16 h = __float2bfloat16(f);
    return __builtin_bit_cast(short, h);
}

// Load 8 consecutive elements as a bf16x8 fragment chunk.
__device__ __forceinline__ bf16x8 ld8(const __hip_bfloat16* p) {
    return *(const bf16x8*)p;
}
__device__ __forceinline__ bf16x8 ld8(const float* p) {
    f32x4 lo = *(const f32x4*)p;
    f32x4 hi = *(const f32x4*)(p + 4);
    bf16x8 r;
#pragma unroll
    for (int i = 0; i < 4; ++i) { r[i] = f2bs(lo[i]); r[4 + i] = f2bs(hi[i]); }
    return r;
}

__device__ __forceinline__ void stv(float* p, long i, float v) { p[i] = v; }
__device__ __forceinline__ void stv(__hip_bfloat16* p, long i, float v) { p[i] = __float2bfloat16(v); }

// C[M,N] = A[M,K] @ B[N,K]^T, MFMA bf16. 128x128 tile, BK=32, 4 waves (64x64 each).
// A/B may be fp32 (converted during staging) or bf16. M%128==0, N%128==0, K%32==0.
template <typename AT, typename BT, typename CT>
__global__ __launch_bounds__(256) void mfma_gemm_bt(const AT* __restrict__ A,
                                                    const BT* __restrict__ B,
                                                    CT* __restrict__ C,
                                                    int M, int N, int K) {
    __shared__ __align__(16) short As[128][40];  // pad 32->40: 2-way bank conflicts only
    __shared__ __align__(16) short Bs[128][40];
    const int tid = threadIdx.x;
    const long bm = (long)blockIdx.y * 128;
    const long bn = (long)blockIdx.x * 128;
    const int lane = tid & 63, wv = tid >> 6;
    const int l15 = lane & 15, quad = lane >> 4;
    const int wm = (wv >> 1) * 64, wn = (wv & 1) * 64;
    f32x4 acc[4][4] = {};
    for (int k0 = 0; k0 < K; k0 += 32) {
#pragma unroll
        for (int i = 0; i < 2; ++i) {
            int ch = tid + 256 * i;              // 512 chunks of 8 elems
            int row = ch >> 2, koff = (ch & 3) * 8;
            *(bf16x8*)&As[row][koff] = ld8(&A[(bm + row) * (long)K + k0 + koff]);
            *(bf16x8*)&Bs[row][koff] = ld8(&B[(bn + row) * (long)K + k0 + koff]);
        }
        __syncthreads();
        bf16x8 af[4], bf[4];
#pragma unroll
        for (int t = 0; t < 4; ++t) {
            af[t] = *(const bf16x8*)&As[wm + t * 16 + l15][quad * 8];
            bf[t] = *(const bf16x8*)&Bs[wn + t * 16 + l15][quad * 8];
        }
#pragma unroll
        for (int mt = 0; mt < 4; ++mt)
#pragma unroll
            for (int nt = 0; nt < 4; ++nt)
                acc[mt][nt] = __builtin_amdgcn_mfma_f32_16x16x32_bf16(af[mt], bf[nt], acc[mt][nt], 0, 0, 0);
        __syncthreads();
    }
#pragma unroll
    for (int mt = 0; mt < 4; ++mt)
#pragma unroll
        for (int nt = 0; nt < 4; ++nt)
#pragma unroll
            for (int r = 0; r < 4; ++r) {
                long row = bm + wm + mt * 16 + quad * 4 + r;   // C/D: row = quad*4+reg
                long col = bn + wn + nt * 16 + l15;            //      col = lane&15
                stv(C, row * N + col, acc[mt][nt][r]);
            }
}

// One MFMA pass of the recurrence: gates[128 x 16] = A[128 x K] @ Bs[16 x K]^T
template <int K>
__device__ __forceinline__ void rec_step(const __hip_bfloat16* __restrict__ Aptr,
                                         const short* BsBase, float* gscBase,
                                         int l15, int quad, int wv) {
    f32x4 acc0 = {0.f, 0.f, 0.f, 0.f}, acc1 = {0.f, 0.f, 0.f, 0.f};
    const long r0 = (long)(wv * 32 + l15);
    const long r1 = r0 + 16;
#pragma unroll
    for (int k0 = 0; k0 < K; k0 += 32) {
        bf16x8 bfr = *(const bf16x8*)(BsBase + l15 * 1032 + k0 + quad * 8);
        bf16x8 a0 = *(const bf16x8*)(Aptr + r0 * K + k0 + quad * 8);
        bf16x8 a1 = *(const bf16x8*)(Aptr + r1 * K + k0 + quad * 8);
        acc0 = __builtin_amdgcn_mfma_f32_16x16x32_bf16(a0, bfr, acc0, 0, 0, 0);
        acc1 = __builtin_amdgcn_mfma_f32_16x16x32_bf16(a1, bfr, acc1, 0, 0, 0);
    }
#pragma unroll
    for (int r = 0; r < 4; ++r) {
        gscBase[(wv * 32 + quad * 4 + r) * 17 + l15] = acc0[r];
        gscBase[(wv * 32 + 16 + quad * 4 + r) * 17 + l15] = acc1[r];
    }
}

// Cooperative full-recurrence kernel. 256 WGs x 256 threads; WG wg owns hidden
// units [wg*4, wg*4+4). Gate cols for unit u, gate g: g*1024 + wg*4 + u.
// LDS B rows: n = g*4 + u (16 rows). c-state in registers (thread owns (b,u)).
__global__ __launch_bounds__(256) void lstm_rec_k(
    const __hip_bfloat16* __restrict__ h0b,   // [128][512]
    const float* __restrict__ c0,             // [128][1024]
    const float* __restrict__ Whh,            // [4096][512] fp32
    const __hip_bfloat16* __restrict__ Wcomb, // [4096][1024]
    const __hip_bfloat16* __restrict__ xg,    // [256][128][4096]
    __hip_bfloat16* __restrict__ hfull,       // [256][128][1024]
    float* __restrict__ cT) {                 // [128][1024]
    __shared__ __align__(16) short Bs[16][1032];  // 33 KB, padded: 2-way conflicts only
    __shared__ float gsc[128][17];
    const int tid = threadIdx.x;
    const int wg = blockIdx.x;
    const int lane = tid & 63, wv = tid >> 6;
    const int l15 = lane & 15, quad = lane >> 4;
    cooperative_groups::grid_group grid = cooperative_groups::this_grid();

    float creg[2];
#pragma unroll
    for (int i = 0; i < 2; ++i) {
        int p = tid + 256 * i, u = p & 3, b = p >> 2;
        creg[i] = c0[b * HH + wg * 4 + u];
    }

    // B for t=0: Whh rows (fp32, K=512)
    for (int ch = tid; ch < 16 * 64; ch += 256) {
        int row = ch >> 6, koff = (ch & 63) * 8;
        long grow = (long)(row >> 2) * HH + wg * 4 + (row & 3);
        *(bf16x8*)&Bs[row][koff] = ld8(&Whh[grow * PP + koff]);
    }
    __syncthreads();

    auto cell = [&](int t) {
        const __hip_bfloat16* xgt = xg + (long)t * BB * GG;
#pragma unroll
        for (int i = 0; i < 2; ++i) {
            int p = tid + 256 * i, u = p & 3, b = p >> 2;
            int hc = wg * 4 + u;
            long xb = (long)b * GG + hc;
            float gi = gsc[b][u]      + __bfloat162float(xgt[xb]);
            float gf = gsc[b][4 + u]  + __bfloat162float(xgt[xb + HH]);
            float gg = gsc[b][8 + u]  + __bfloat162float(xgt[xb + 2 * HH]);
            float go = gsc[b][12 + u] + __bfloat162float(xgt[xb + 3 * HH]);
            float i_ = 1.f / (1.f + expf(-gi));
            float f_ = 1.f / (1.f + expf(-gf));
            float g_ = tanhf(gg);
            float o_ = 1.f / (1.f + expf(-go));
            float c = f_ * creg[i] + i_ * g_;
            creg[i] = c;
            hfull[(long)t * BB * HH + (long)b * HH + hc] = __float2bfloat16(o_ * tanhf(c));
        }
    };

    // t = 0: A = h0 (K=512), B = Whh
    rec_step<PP>(h0b, &Bs[0][0], &gsc[0][0], l15, quad, wv);
    __syncthreads();
    cell(0);
    __threadfence();
    grid.sync();

    // B for t>=1: Wcomb rows (bf16, K=1024)
    for (int ch = tid; ch < 16 * 128; ch += 256) {
        int row = ch >> 7, koff = (ch & 127) * 8;
        long grow = (long)(row >> 2) * HH + wg * 4 + (row & 3);
        *(bf16x8*)&Bs[row][koff] = *(const bf16x8*)&Wcomb[grow * HH + koff];
    }
    __syncthreads();

    for (int t = 1; t < TS; ++t) {
        rec_step<HH>(hfull + (long)(t - 1) * BB * HH, &Bs[0][0], &gsc[0][0], l15, quad, wv);
        __syncthreads();
        cell(t);
        __threadfence();
        grid.sync();
    }

#pragma unroll
    for (int i = 0; i < 2; ++i) {
        int p = tid + 256 * i, u = p & 3, b = p >> 2;
        cT[(long)b * HH + wg * 4 + u] = creg[i];
    }
}

// h0 cast to bf16; Whr transpose (fp32) for the Wcomb GEMM.
__global__ __launch_bounds__(256) void prep_k(const float* __restrict__ h0,
                                              __hip_bfloat16* __restrict__ h0b,
                                              const float* __restrict__ Whr,
                                              float* __restrict__ WhrT) {
    int i = blockIdx.x * 256 + threadIdx.x;  // grid covers PP*HH
    if (i < BB * PP) h0b[i] = __float2bfloat16(h0[i]);
    if (i < PP * HH) {
        int h = i / PP, p = i % PP;
        WhrT[i] = Whr[(long)p * HH + h];
    }
}

__global__ __launch_bounds__(256) void tail_k(const float* __restrict__ ys_last,
                                              float* __restrict__ hT) {
    int i = blockIdx.x * 256 + threadIdx.x;  // B*P
    hT[i] = ys_last[i];
}

extern "C" void kernel_launch(void* const* d_in, const int* in_sizes, int n_in,
                              void* d_out, int out_size, void* d_ws, size_t ws_size,
                              hipStream_t stream) {
    const float* x   = (const float*)d_in[0];  // [T,B,I]
    const float* h0  = (const float*)d_in[1];  // [1,B,P]
    const float* c0  = (const float*)d_in[2];  // [1,B,H]
    const float* Wih = (const float*)d_in[3];  // [4H,I]
    const float* Whh = (const float*)d_in[4];  // [4H,P]
    const float* Whr = (const float*)d_in[5];  // [P,H]

    float* out = (float*)d_out;
    float* ys = out;                           // [T,B,P]
    float* hT = out + (long)TS * BB * PP;      // [B,P]
    float* cT = hT + (long)BB * PP;            // [B,H]

    char* ws = (char*)d_ws;
    size_t off = 0;
    __hip_bfloat16* xg = (__hip_bfloat16*)(ws + off);    off += (size_t)TS * BB * GG * 2;  // 268 MB
    __hip_bfloat16* hfull = (__hip_bfloat16*)(ws + off); off += (size_t)TS * BB * HH * 2;  // 67 MB
    __hip_bfloat16* Wcomb = (__hip_bfloat16*)(ws + off); off += (size_t)GG * HH * 2;       // 8.4 MB
    float* WhrT = (float*)(ws + off);                    off += (size_t)HH * PP * 4;       // 2 MB
    __hip_bfloat16* h0b = (__hip_bfloat16*)(ws + off);   off += (size_t)BB * PP * 2;       // 128 KB

    dim3 blk(256);

    // prep: h0 -> bf16, Whr -> WhrT (fp32)
    prep_k<<<dim3((PP * HH) / 256), blk, 0, stream>>>(h0, h0b, Whr, WhrT);

    // xg[T*B, 4H] = x @ W_ih^T  (fp32 in, bf16 out, MFMA)
    mfma_gemm_bt<float, float, __hip_bfloat16>
        <<<dim3(GG / 128, (TS * BB) / 128), blk, 0, stream>>>(x, Wih, xg, TS * BB, GG, II);

    // W_comb[4H, H] = W_hh @ W_hr  via bt-GEMM with B = WhrT
    mfma_gemm_bt<float, float, __hip_bfloat16>
        <<<dim3(HH / 128, GG / 128), blk, 0, stream>>>(Whh, WhrT, Wcomb, GG, HH, PP);

    // full recurrence (cooperative, one launch, 256 grid syncs)
    {
        const __hip_bfloat16* a0 = h0b;
        const float* a1 = c0;
        const float* a2 = Whh;
        const __hip_bfloat16* a3 = Wcomb;
        const __hip_bfloat16* a4 = xg;
        __hip_bfloat16* a5 = hfull;
        float* a6 = cT;
        void* args[] = {(void*)&a0, (void*)&a1, (void*)&a2, (void*)&a3,
                        (void*)&a4, (void*)&a5, (void*)&a6};
        hipLaunchCooperativeKernel(reinterpret_cast<void*>(lstm_rec_k),
                                   dim3(256), blk, args, 0, stream);
    }

    // ys[T*B, P] = hfull @ W_hr^T  (bf16 A, fp32 B, fp32 out)
    mfma_gemm_bt<__hip_bfloat16, float, float>
        <<<dim3(PP / 128, (TS * BB) / 128), blk, 0, stream>>>(hfull, Whr, ys, TS * BB, PP, HH);

    // hT = ys[T-1]
    tail_k<<<dim3((BB * PP) / 256), blk, 0, stream>>>(ys + (long)(TS - 1) * BB * PP, hT);
}

// Round 4
// 6582.954 us; speedup vs baseline: 3.8581x; 2.7680x over previous
//
#include <hip/hip_runtime.h>
#include <hip/hip_bf16.h>

#define TS 256
#define BB 128
#define II 1024
#define HH 1024
#define PP 512
#define GG 4096  // 4*H
#define NWG 256

typedef __attribute__((ext_vector_type(8))) short bf16x8;
typedef __attribute__((ext_vector_type(4))) float f32x4;

__device__ __forceinline__ short f2bs(float f) {
    __hip_bfloat16 h = __float2bfloat16(f);
    return __builtin_bit_cast(short, h);
}

__device__ __forceinline__ bf16x8 ld8(const __hip_bfloat16* p) {
    return *(const bf16x8*)p;
}
__device__ __forceinline__ bf16x8 ld8(const float* p) {
    f32x4 lo = *(const f32x4*)p;
    f32x4 hi = *(const f32x4*)(p + 4);
    bf16x8 r;
#pragma unroll
    for (int i = 0; i < 4; ++i) { r[i] = f2bs(lo[i]); r[4 + i] = f2bs(hi[i]); }
    return r;
}

__device__ __forceinline__ void stv(float* p, long i, float v) { p[i] = v; }
__device__ __forceinline__ void stv(__hip_bfloat16* p, long i, float v) { p[i] = __float2bfloat16(v); }

// C[M,N] = A[M,K] @ B[N,K]^T, MFMA bf16. 128x128 tile, BK=32, 4 waves (64x64 each).
template <typename AT, typename BT, typename CT>
__global__ __launch_bounds__(256) void mfma_gemm_bt(const AT* __restrict__ A,
                                                    const BT* __restrict__ B,
                                                    CT* __restrict__ C,
                                                    int M, int N, int K) {
    __shared__ __align__(16) short As[128][40];
    __shared__ __align__(16) short Bs[128][40];
    const int tid = threadIdx.x;
    const long bm = (long)blockIdx.y * 128;
    const long bn = (long)blockIdx.x * 128;
    const int lane = tid & 63, wv = tid >> 6;
    const int l15 = lane & 15, quad = lane >> 4;
    const int wm = (wv >> 1) * 64, wn = (wv & 1) * 64;
    f32x4 acc[4][4] = {};
    for (int k0 = 0; k0 < K; k0 += 32) {
#pragma unroll
        for (int i = 0; i < 2; ++i) {
            int ch = tid + 256 * i;
            int row = ch >> 2, koff = (ch & 3) * 8;
            *(bf16x8*)&As[row][koff] = ld8(&A[(bm + row) * (long)K + k0 + koff]);
            *(bf16x8*)&Bs[row][koff] = ld8(&B[(bn + row) * (long)K + k0 + koff]);
        }
        __syncthreads();
        bf16x8 af[4], bf[4];
#pragma unroll
        for (int t = 0; t < 4; ++t) {
            af[t] = *(const bf16x8*)&As[wm + t * 16 + l15][quad * 8];
            bf[t] = *(const bf16x8*)&Bs[wn + t * 16 + l15][quad * 8];
        }
#pragma unroll
        for (int mt = 0; mt < 4; ++mt)
#pragma unroll
            for (int nt = 0; nt < 4; ++nt)
                acc[mt][nt] = __builtin_amdgcn_mfma_f32_16x16x32_bf16(af[mt], bf[nt], acc[mt][nt], 0, 0, 0);
        __syncthreads();
    }
#pragma unroll
    for (int mt = 0; mt < 4; ++mt)
#pragma unroll
        for (int nt = 0; nt < 4; ++nt)
#pragma unroll
            for (int r = 0; r < 4; ++r) {
                long row = bm + wm + mt * 16 + quad * 4 + r;
                long col = bn + wn + nt * 16 + l15;
                stv(C, row * N + col, acc[mt][nt][r]);
            }
}

// Custom grid barrier: monotonic counter in global memory, generation = target.
// Agent-scope release/acquire fences give cross-XCD visibility of hfull writes.
__device__ __forceinline__ void gbar(unsigned* bar, unsigned target) {
    __syncthreads();
    if (threadIdx.x == 0) {
        __builtin_amdgcn_fence(__ATOMIC_RELEASE, "agent");
        __hip_atomic_fetch_add(bar, 1u, __ATOMIC_RELAXED, __HIP_MEMORY_SCOPE_AGENT);
        while (__hip_atomic_load(bar, __ATOMIC_RELAXED, __HIP_MEMORY_SCOPE_AGENT) < target) {
            __builtin_amdgcn_s_sleep(1);
        }
        __builtin_amdgcn_fence(__ATOMIC_ACQUIRE, "agent");
    }
    __syncthreads();
}

// One MFMA pass of the recurrence: gates[128 x 16] = A[128 x K] @ Bs[16 x K]^T
template <int K>
__device__ __forceinline__ void rec_step(const __hip_bfloat16* __restrict__ Aptr,
                                         const short* BsBase, float* gscBase,
                                         int l15, int quad, int wv) {
    f32x4 acc0 = {0.f, 0.f, 0.f, 0.f}, acc1 = {0.f, 0.f, 0.f, 0.f};
    const long r0 = (long)(wv * 32 + l15);
    const long r1 = r0 + 16;
#pragma unroll
    for (int k0 = 0; k0 < K; k0 += 32) {
        bf16x8 bfr = *(const bf16x8*)(BsBase + l15 * 1032 + k0 + quad * 8);
        bf16x8 a0 = *(const bf16x8*)(Aptr + r0 * K + k0 + quad * 8);
        bf16x8 a1 = *(const bf16x8*)(Aptr + r1 * K + k0 + quad * 8);
        acc0 = __builtin_amdgcn_mfma_f32_16x16x32_bf16(a0, bfr, acc0, 0, 0, 0);
        acc1 = __builtin_amdgcn_mfma_f32_16x16x32_bf16(a1, bfr, acc1, 0, 0, 0);
    }
#pragma unroll
    for (int r = 0; r < 4; ++r) {
        gscBase[(wv * 32 + quad * 4 + r) * 17 + l15] = acc0[r];
        gscBase[(wv * 32 + 16 + quad * 4 + r) * 17 + l15] = acc1[r];
    }
}

// Cooperative full-recurrence kernel: 256 WGs x 256 threads, WG owns 4 hidden cols.
__global__ __launch_bounds__(256) void lstm_rec_k(
    const __hip_bfloat16* __restrict__ h0b,   // [128][512]
    const float* __restrict__ c0,             // [128][1024]
    const float* __restrict__ Whh,            // [4096][512] fp32
    const __hip_bfloat16* __restrict__ Wcomb, // [4096][1024]
    const __hip_bfloat16* __restrict__ xg,    // [256][128][4096]
    __hip_bfloat16* __restrict__ hfull,       // [256][128][1024]
    float* __restrict__ cT,                   // [128][1024]
    unsigned* __restrict__ bar) {
    __shared__ __align__(16) short Bs[16][1032];
    __shared__ float gsc[128][17];
    const int tid = threadIdx.x;
    const int wg = blockIdx.x;
    const int lane = tid & 63, wv = tid >> 6;
    const int l15 = lane & 15, quad = lane >> 4;

    float creg[2];
#pragma unroll
    for (int i = 0; i < 2; ++i) {
        int p = tid + 256 * i, u = p & 3, b = p >> 2;
        creg[i] = c0[b * HH + wg * 4 + u];
    }

    // B for t=0: Whh rows (fp32, K=512)
    for (int ch = tid; ch < 16 * 64; ch += 256) {
        int row = ch >> 6, koff = (ch & 63) * 8;
        long grow = (long)(row >> 2) * HH + wg * 4 + (row & 3);
        *(bf16x8*)&Bs[row][koff] = ld8(&Whh[grow * PP + koff]);
    }
    __syncthreads();

    auto cell = [&](int t) {
        const __hip_bfloat16* xgt = xg + (long)t * BB * GG;
#pragma unroll
        for (int i = 0; i < 2; ++i) {
            int p = tid + 256 * i, u = p & 3, b = p >> 2;
            int hc = wg * 4 + u;
            long xb = (long)b * GG + hc;
            float gi = gsc[b][u]      + __bfloat162float(xgt[xb]);
            float gf = gsc[b][4 + u]  + __bfloat162float(xgt[xb + HH]);
            float gg = gsc[b][8 + u]  + __bfloat162float(xgt[xb + 2 * HH]);
            float go = gsc[b][12 + u] + __bfloat162float(xgt[xb + 3 * HH]);
            float i_ = 1.f / (1.f + expf(-gi));
            float f_ = 1.f / (1.f + expf(-gf));
            float g_ = tanhf(gg);
            float o_ = 1.f / (1.f + expf(-go));
            float c = f_ * creg[i] + i_ * g_;
            creg[i] = c;
            hfull[(long)t * BB * HH + (long)b * HH + hc] = __float2bfloat16(o_ * tanhf(c));
        }
    };

    // t = 0: A = h0 (K=512), B = Whh
    rec_step<PP>(h0b, &Bs[0][0], &gsc[0][0], l15, quad, wv);
    __syncthreads();
    cell(0);
    gbar(bar, NWG);

    // B for t>=1: Wcomb rows (bf16, K=1024)
    for (int ch = tid; ch < 16 * 128; ch += 256) {
        int row = ch >> 7, koff = (ch & 127) * 8;
        long grow = (long)(row >> 2) * HH + wg * 4 + (row & 3);
        *(bf16x8*)&Bs[row][koff] = *(const bf16x8*)&Wcomb[grow * HH + koff];
    }
    __syncthreads();

    for (int t = 1; t < TS; ++t) {
        rec_step<HH>(hfull + (long)(t - 1) * BB * HH, &Bs[0][0], &gsc[0][0], l15, quad, wv);
        __syncthreads();
        cell(t);
        if (t < TS - 1) gbar(bar, (unsigned)(t + 1) * NWG);
    }

#pragma unroll
    for (int i = 0; i < 2; ++i) {
        int p = tid + 256 * i, u = p & 3, b = p >> 2;
        cT[(long)b * HH + wg * 4 + u] = creg[i];
    }
}

// h0 cast to bf16; Whr transpose (fp32); zero the barrier counter.
__global__ __launch_bounds__(256) void prep_k(const float* __restrict__ h0,
                                              __hip_bfloat16* __restrict__ h0b,
                                              const float* __restrict__ Whr,
                                              float* __restrict__ WhrT,
                                              unsigned* __restrict__ bar) {
    int i = blockIdx.x * 256 + threadIdx.x;
    if (i == 0) *bar = 0u;
    if (i < BB * PP) h0b[i] = __float2bfloat16(h0[i]);
    if (i < PP * HH) {
        int h = i / PP, p = i % PP;
        WhrT[i] = Whr[(long)p * HH + h];
    }
}

__global__ __launch_bounds__(256) void tail_k(const float* __restrict__ ys_last,
                                              float* __restrict__ hT) {
    int i = blockIdx.x * 256 + threadIdx.x;
    hT[i] = ys_last[i];
}

extern "C" void kernel_launch(void* const* d_in, const int* in_sizes, int n_in,
                              void* d_out, int out_size, void* d_ws, size_t ws_size,
                              hipStream_t stream) {
    const float* x   = (const float*)d_in[0];  // [T,B,I]
    const float* h0  = (const float*)d_in[1];  // [1,B,P]
    const float* c0  = (const float*)d_in[2];  // [1,B,H]
    const float* Wih = (const float*)d_in[3];  // [4H,I]
    const float* Whh = (const float*)d_in[4];  // [4H,P]
    const float* Whr = (const float*)d_in[5];  // [P,H]

    float* out = (float*)d_out;
    float* ys = out;                           // [T,B,P]
    float* hT = out + (long)TS * BB * PP;      // [B,P]
    float* cT = hT + (long)BB * PP;            // [B,H]

    char* ws = (char*)d_ws;
    size_t off = 0;
    __hip_bfloat16* xg = (__hip_bfloat16*)(ws + off);    off += (size_t)TS * BB * GG * 2;
    __hip_bfloat16* hfull = (__hip_bfloat16*)(ws + off); off += (size_t)TS * BB * HH * 2;
    __hip_bfloat16* Wcomb = (__hip_bfloat16*)(ws + off); off += (size_t)GG * HH * 2;
    float* WhrT = (float*)(ws + off);                    off += (size_t)HH * PP * 4;
    __hip_bfloat16* h0b = (__hip_bfloat16*)(ws + off);   off += (size_t)BB * PP * 2;
    unsigned* bar = (unsigned*)(ws + off);               off += 256;

    dim3 blk(256);

    // prep: h0 -> bf16, Whr -> WhrT, zero barrier
    prep_k<<<dim3((PP * HH) / 256), blk, 0, stream>>>(h0, h0b, Whr, WhrT, bar);

    // xg[T*B, 4H] = x @ W_ih^T
    mfma_gemm_bt<float, float, __hip_bfloat16>
        <<<dim3(GG / 128, (TS * BB) / 128), blk, 0, stream>>>(x, Wih, xg, TS * BB, GG, II);

    // W_comb[4H, H] = W_hh @ W_hr
    mfma_gemm_bt<float, float, __hip_bfloat16>
        <<<dim3(HH / 128, GG / 128), blk, 0, stream>>>(Whh, WhrT, Wcomb, GG, HH, PP);

    // full recurrence (cooperative launch for co-residency; custom barrier inside)
    {
        const __hip_bfloat16* a0 = h0b;
        const float* a1 = c0;
        const float* a2 = Whh;
        const __hip_bfloat16* a3 = Wcomb;
        const __hip_bfloat16* a4 = xg;
        __hip_bfloat16* a5 = hfull;
        float* a6 = cT;
        unsigned* a7 = bar;
        void* args[] = {(void*)&a0, (void*)&a1, (void*)&a2, (void*)&a3,
                        (void*)&a4, (void*)&a5, (void*)&a6, (void*)&a7};
        (void)hipLaunchCooperativeKernel(reinterpret_cast<void*>(lstm_rec_k),
                                         dim3(NWG), blk, args, 0, stream);
    }

    // ys[T*B, P] = hfull @ W_hr^T
    mfma_gemm_bt<__hip_bfloat16, float, float>
        <<<dim3(PP / 128, (TS * BB) / 128), blk, 0, stream>>>(hfull, Whr, ys, TS * BB, PP, HH);

    // hT = ys[T-1]
    tail_k<<<dim3((BB * PP) / 256), blk, 0, stream>>>(ys + (long)(TS - 1) * BB * PP, hT);
}